// Round 5
// baseline (357.256 us; speedup 1.0000x reference)
//
#include <hip/hip_runtime.h>
#include <hip/hip_bf16.h>
#include <cstdint>
#include <cstddef>

typedef __bf16 bf16;
typedef __attribute__((ext_vector_type(2))) __bf16 bf16x2;
typedef __attribute__((ext_vector_type(4))) __bf16 bf16x4;
typedef __attribute__((ext_vector_type(8))) __bf16 bf16x8;
typedef __attribute__((ext_vector_type(4))) float f32x4;

#define MFMA16(a, b, c) __builtin_amdgcn_mfma_f32_16x16x32_bf16((a), (b), (c), 0, 0, 0)
// softmax runs in exp2 domain: scores scaled by (1/sqrt(128))*log2(e)
#define SCALE_L2E 0.127517432f

// Packed-layout constants:
//  QCR row: [0..2047]=q_c (h*128+d), [2048..3071]=q_r (h*64+r)    stride 3072
//  KVKR row: [0..2047]=k_c, [2048..4095]=v, [4096..4159]=k_r      stride 4160
#define QCR_STRIDE 3072
#define KV_STRIDE  4160

__device__ __forceinline__ void gload16(const void* g, void* l) {
    __builtin_amdgcn_global_load_lds(
        (const __attribute__((address_space(1))) void*)g,
        (__attribute__((address_space(3))) void*)l, 16, 0, 0);
}

// ---------------- f32 -> bf16 transpose-convert (weights) ----------------
__global__ __launch_bounds__(256) void k_cvtT(const float* __restrict__ in,
                                              bf16* __restrict__ out, int Kd, int Nd)
{
    __shared__ float tile[32][33];
    const int k0 = blockIdx.y * 32, n0 = blockIdx.x * 32;
    const int t = threadIdx.x;
    const int r = t >> 3, c4 = (t & 7) * 4;
    float4 v = *(const float4*)(in + (size_t)(k0 + r) * Nd + n0 + c4);
    tile[r][c4 + 0] = v.x; tile[r][c4 + 1] = v.y;
    tile[r][c4 + 2] = v.z; tile[r][c4 + 3] = v.w;
    __syncthreads();
    bf16x4 o;
    o[0] = (bf16)tile[c4 + 0][r]; o[1] = (bf16)tile[c4 + 1][r];
    o[2] = (bf16)tile[c4 + 2][r]; o[3] = (bf16)tile[c4 + 3][r];
    *(bf16x4*)(out + (size_t)(n0 + r) * Kd + k0 + c4) = o;
}

// ---------------- bf16 MFMA GEMM, B pre-transposed, 2-phase dbuf ----------------
template<bool AF32, bool F32OUT>
__global__ __launch_bounds__(256) void k_gemm_bt(
    const bf16* __restrict__ A, const float* __restrict__ Af,
    const bf16* __restrict__ BT,
    bf16* __restrict__ Cb, float* __restrict__ Cf,
    int M, int N, int K, int lda)
{
    __shared__ bf16 As[2][4096];   // [128 rows][32 k] linear
    __shared__ bf16 Bs[2][4096];   // [128 n-rows][32 k] linear

    const int t = threadIdx.x;
    const int m0 = blockIdx.y * 128;
    const int n0 = blockIdx.x * 128;
    const int wid = t >> 6, lane = t & 63;
    const int wm = (wid >> 1) * 64, wn = (wid & 1) * 64;
    const int lr = lane & 15, lk = (lane >> 4) * 8;

    const int srow = t >> 2, skc = (t & 3) << 3;
    const int bn0 = min(n0 + srow, N - 1);
    const int bn1 = min(n0 + srow + 64, N - 1);

    f32x4 acc[4][4];
    const f32x4 z = {0.f, 0.f, 0.f, 0.f};
#pragma unroll
    for (int m = 0; m < 4; ++m)
#pragma unroll
        for (int n = 0; n < 4; ++n) acc[m][n] = z;

    auto stage = [&](int buf, int k0) {
        gload16(BT + (size_t)bn0 * K + k0 + skc, &Bs[buf][t * 8]);
        gload16(BT + (size_t)bn1 * K + k0 + skc, &Bs[buf][(t + 256) * 8]);
        if constexpr (AF32) {
            const float* s0 = Af + (size_t)(m0 + srow) * lda + k0 + skc;
            float4 u0 = *(const float4*)s0;
            float4 u1 = *(const float4*)(s0 + 4);
            bf16x8 v;
            v[0] = (bf16)u0.x; v[1] = (bf16)u0.y; v[2] = (bf16)u0.z; v[3] = (bf16)u0.w;
            v[4] = (bf16)u1.x; v[5] = (bf16)u1.y; v[6] = (bf16)u1.z; v[7] = (bf16)u1.w;
            *(bf16x8*)(&As[buf][t * 8]) = v;
            const float* s1 = Af + (size_t)(m0 + srow + 64) * lda + k0 + skc;
            float4 w0 = *(const float4*)s1;
            float4 w1 = *(const float4*)(s1 + 4);
            bf16x8 v2;
            v2[0] = (bf16)w0.x; v2[1] = (bf16)w0.y; v2[2] = (bf16)w0.z; v2[3] = (bf16)w0.w;
            v2[4] = (bf16)w1.x; v2[5] = (bf16)w1.y; v2[6] = (bf16)w1.z; v2[7] = (bf16)w1.w;
            *(bf16x8*)(&As[buf][(t + 256) * 8]) = v2;
        } else {
            gload16(A + (size_t)(m0 + srow) * lda + k0 + skc, &As[buf][t * 8]);
            gload16(A + (size_t)(m0 + srow + 64) * lda + k0 + skc, &As[buf][(t + 256) * 8]);
        }
    };

    stage(0, 0);
    __syncthreads();

    for (int k0 = 0; k0 < K; k0 += 32) {
        const int cur = (k0 >> 5) & 1;
        if (k0 + 32 < K) stage(cur ^ 1, k0 + 32);

        bf16x8 af[4], bfr[4];
#pragma unroll
        for (int m = 0; m < 4; ++m) af[m] = *(const bf16x8*)(&As[cur][(wm + m * 16 + lr) * 32 + lk]);
#pragma unroll
        for (int n = 0; n < 4; ++n) bfr[n] = *(const bf16x8*)(&Bs[cur][(wn + n * 16 + lr) * 32 + lk]);
#pragma unroll
        for (int m = 0; m < 4; ++m)
#pragma unroll
            for (int n = 0; n < 4; ++n)
                acc[m][n] = MFMA16(af[m], bfr[n], acc[m][n]);

        __syncthreads();
    }

    const int lrow4 = (lane >> 4) * 4;
#pragma unroll
    for (int m = 0; m < 4; ++m)
#pragma unroll
        for (int n = 0; n < 4; ++n)
#pragma unroll
            for (int i = 0; i < 4; ++i) {
                int r = m0 + wm + m * 16 + lrow4 + i;
                int c = n0 + wn + n * 16 + lr;
                if (r < M && c < N) {
                    if constexpr (F32OUT) Cf[(size_t)r * N + c] = acc[m][n][i];
                    else Cb[(size_t)r * N + c] = (bf16)acc[m][n][i];
                }
            }
}

// ---------------- RoPE (in-place, bf16, packed layouts) ----------------
__global__ void k_rope_q(bf16* __restrict__ qcr)
{
    int idx = blockIdx.x * blockDim.x + threadIdx.x;  // 4096*512 threads
    int row = idx >> 9;
    int rem = idx & 511;
    int h = rem >> 5;
    int i = rem & 31;
    int s = row & 2047;
    float ang = (float)s * __expf(-(float)i * 0.28782313662f);  // ln(10000)/32
    float c = cosf(ang), sn = sinf(ang);
    size_t base = (size_t)row * QCR_STRIDE + 2048 + h * 64 + (i << 1);
    float xe = (float)qcr[base], xo = (float)qcr[base + 1];
    qcr[base] = (bf16)(xe * c - xo * sn);
    qcr[base + 1] = (bf16)(xe * sn + xo * c);
}

__global__ void k_rope_k(bf16* __restrict__ kvkr)
{
    int idx = blockIdx.x * blockDim.x + threadIdx.x;  // 4096*32 threads
    int row = idx >> 5;
    int i = idx & 31;
    int s = row & 2047;
    float ang = (float)s * __expf(-(float)i * 0.28782313662f);
    float c = cosf(ang), sn = sinf(ang);
    size_t base = (size_t)row * KV_STRIDE + 4096 + (i << 1);
    float xe = (float)kvkr[base], xo = (float)kvkr[base + 1];
    kvkr[base] = (bf16)(xe * c - xo * sn);
    kvkr[base + 1] = (bf16)(xe * sn + xo * c);
}

// ---------------- causal MLA attention ----------------
// 512 blocks, each ONE 128-row q-tile; 4 waves x 32 q-rows (2 m-frags/wave).
// blockIdx ordered heavy-first (qt descends) for LPT balance.
__global__ __launch_bounds__(256, 2) void k_attn(
    const bf16* __restrict__ qcr, const bf16* __restrict__ kvkr,
    bf16* __restrict__ att)
{
    __shared__ bf16 Ks[64 * 200];   // [key][feat 0..191], stride 200
    __shared__ bf16 Vt[128 * 72];   // [feat][key], stride 72
    __shared__ bf16 Pw[4][32 * 72]; // per-wave P tile [32 rows][64 keys]

    const int L = blockIdx.x;
    const int qt = 15 - (L >> 5);     // 128-row q-tile index, heavy first
    const int bh = L & 31;
    const int h = bh & 15, b = bh >> 4;

    const int t = threadIdx.x;
    const int wid = t >> 6, lane = t & 63;
    const int lr = lane & 15, lk = (lane >> 4) * 8, lrow4 = (lane >> 4) * 4;
    const size_t rowbase = (size_t)b * 2048;

    const int vkp = lane & 31;              // key-pair 0..31 (spreads write banks)
    const int vf0 = (lane >> 5) + 2 * wid;  // feat-chunk base 0..7

    const int qrow_w = qt * 128 + wid * 32; // wave's first q-row

    const f32x4 z = {0.f, 0.f, 0.f, 0.f};

    // Q fragments for both 16-row m-frags
    bf16x8 qf[2][6];
#pragma unroll
    for (int ma = 0; ma < 2; ++ma) {
        const size_t qrow = rowbase + qrow_w + ma * 16 + lr;
        const bf16* qp = qcr + qrow * QCR_STRIDE + h * 128;
#pragma unroll
        for (int ks = 0; ks < 4; ++ks) qf[ma][ks] = *(const bf16x8*)(qp + ks * 32 + lk);
        const bf16* qp2 = qcr + qrow * QCR_STRIDE + 2048 + h * 64;
#pragma unroll
        for (int ks = 0; ks < 2; ++ks) qf[ma][4 + ks] = *(const bf16x8*)(qp2 + ks * 32 + lk);
    }

    float mrow[2][4], lsum[2][4];
    f32x4 o[2][8];
#pragma unroll
    for (int ma = 0; ma < 2; ++ma) {
#pragma unroll
        for (int i = 0; i < 4; ++i) { mrow[ma][i] = -3e38f; lsum[ma][i] = 0.f; }
#pragma unroll
        for (int n = 0; n < 8; ++n) o[ma][n] = z;
    }

    const int nkt = 2 * qt + 2;
#pragma unroll 1
    for (int kt = 0; kt < nkt; ++kt) {
        const int kb = kt * 64;
        __syncthreads();
        // ---- stage K_c 64x128 ----
#pragma unroll
        for (int i = 0; i < 4; ++i) {
            int idx = t + i * 256;
            int row = idx >> 4, fc = (idx & 15) << 3;
            bf16x8 v = *(const bf16x8*)(kvkr + (rowbase + kb + row) * KV_STRIDE + h * 128 + fc);
            *(bf16x8*)(Ks + row * 200 + fc) = v;
        }
        // ---- stage K_r 64x64 ----
#pragma unroll
        for (int i = 0; i < 2; ++i) {
            int idx = t + i * 256;
            int row = idx >> 3, fc = (idx & 7) << 3;
            bf16x8 v = *(const bf16x8*)(kvkr + (rowbase + kb + row) * KV_STRIDE + 4096 + fc);
            *(bf16x8*)(Ks + row * 200 + 128 + fc) = v;
        }
        // ---- stage V 64x128 -> Vt[feat][key], 2-way-bank dword-pair writes ----
#pragma unroll
        for (int it = 0; it < 2; ++it) {
            const int fci = vf0 + 8 * it;
            const bf16* vs = kvkr + (rowbase + kb + 2 * vkp) * KV_STRIDE + 2048 + h * 128 + fci * 8;
            bf16x8 v0 = *(const bf16x8*)vs;
            bf16x8 v1 = *(const bf16x8*)(vs + KV_STRIDE);
#pragma unroll
            for (int j = 0; j < 8; ++j) {
                bf16x2 pr; pr[0] = v0[j]; pr[1] = v1[j];
                *(bf16x2*)(Vt + (fci * 8 + j) * 72 + 2 * vkp) = pr;
            }
        }
        __syncthreads();

        // waves whose rows are ALL below this key tile skip compute entirely
        if (kb <= qrow_w + 31) {
            // ---- S = Q K^T (both m-frags share each kf read) ----
            f32x4 sacc[2][4];
#pragma unroll
            for (int kg = 0; kg < 4; ++kg) {
                f32x4 s0 = z, s1 = z;
#pragma unroll
                for (int ks = 0; ks < 6; ++ks) {
                    bf16x8 kf = *(const bf16x8*)(Ks + (kg * 16 + lr) * 200 + ks * 32 + lk);
                    s0 = MFMA16(qf[0][ks], kf, s0);
                    s1 = MFMA16(qf[1][ks], kf, s1);
                }
                sacc[0][kg] = s0; sacc[1][kg] = s1;
            }

            // ---- scale (exp2 domain) + causal mask + row max ----
            const bool domask = (kb + 63) > qrow_w;
            float rmax[2][4];
#pragma unroll
            for (int ma = 0; ma < 2; ++ma)
#pragma unroll
                for (int i = 0; i < 4; ++i) {
                    int qi = qrow_w + ma * 16 + lrow4 + i;
                    float mx = -3e38f;
#pragma unroll
                    for (int kg = 0; kg < 4; ++kg) {
                        float v = sacc[ma][kg][i] * SCALE_L2E;
                        if (domask && (kb + kg * 16 + lr) > qi) v = -3e38f;
                        sacc[ma][kg][i] = v;
                        mx = fmaxf(mx, v);
                    }
                    rmax[ma][i] = mx;
                }
#pragma unroll
            for (int d = 1; d < 16; d <<= 1)
#pragma unroll
                for (int ma = 0; ma < 2; ++ma)
#pragma unroll
                    for (int i = 0; i < 4; ++i)
                        rmax[ma][i] = fmaxf(rmax[ma][i], __shfl_xor(rmax[ma][i], d, 64));

            // ---- defer-max: rescale only if some row got a new max ----
            int anynew = 0;
#pragma unroll
            for (int ma = 0; ma < 2; ++ma)
#pragma unroll
                for (int i = 0; i < 4; ++i)
                    if (rmax[ma][i] > mrow[ma][i]) anynew = 1;
            if (__any(anynew)) {
#pragma unroll
                for (int ma = 0; ma < 2; ++ma)
#pragma unroll
                    for (int i = 0; i < 4; ++i) {
                        float mnew = fmaxf(mrow[ma][i], rmax[ma][i]);
                        float scl = __builtin_amdgcn_exp2f(mrow[ma][i] - mnew);
                        mrow[ma][i] = mnew;
                        lsum[ma][i] *= scl;
#pragma unroll
                        for (int n = 0; n < 8; ++n) o[ma][n][i] *= scl;
                    }
            }

            // ---- P = exp2(S - m), row sums ----
            float rsum[2][4] = {{0.f,0.f,0.f,0.f},{0.f,0.f,0.f,0.f}};
#pragma unroll
            for (int ma = 0; ma < 2; ++ma)
#pragma unroll
                for (int kg = 0; kg < 4; ++kg)
#pragma unroll
                    for (int i = 0; i < 4; ++i) {
                        float pv = __builtin_amdgcn_exp2f(sacc[ma][kg][i] - mrow[ma][i]);
                        sacc[ma][kg][i] = pv;
                        rsum[ma][i] += pv;
                    }
#pragma unroll
            for (int d = 1; d < 16; d <<= 1)
#pragma unroll
                for (int ma = 0; ma < 2; ++ma)
#pragma unroll
                    for (int i = 0; i < 4; ++i) rsum[ma][i] += __shfl_xor(rsum[ma][i], d, 64);
#pragma unroll
            for (int ma = 0; ma < 2; ++ma)
#pragma unroll
                for (int i = 0; i < 4; ++i) lsum[ma][i] += rsum[ma][i];

            // ---- P -> per-wave LDS (re-fragment for PV A-operand) ----
#pragma unroll
            for (int ma = 0; ma < 2; ++ma)
#pragma unroll
                for (int kg = 0; kg < 4; ++kg)
#pragma unroll
                    for (int i = 0; i < 4; ++i)
                        Pw[wid][(ma * 16 + lrow4 + i) * 72 + kg * 16 + lr] = (bf16)sacc[ma][kg][i];

            // ---- O += P V (vf shared by both m-frags) ----
#pragma unroll
            for (int ks = 0; ks < 2; ++ks) {
                bf16x8 pa0 = *(const bf16x8*)(&Pw[wid][lr * 72 + ks * 32 + lk]);
                bf16x8 pa1 = *(const bf16x8*)(&Pw[wid][(16 + lr) * 72 + ks * 32 + lk]);
#pragma unroll
                for (int n = 0; n < 8; ++n) {
                    bf16x8 vf = *(const bf16x8*)(Vt + (n * 16 + lr) * 72 + ks * 32 + lk);
                    o[0][n] = MFMA16(pa0, vf, o[0][n]);
                    o[1][n] = MFMA16(pa1, vf, o[1][n]);
                }
            }
        }
    }

#pragma unroll
    for (int ma = 0; ma < 2; ++ma)
#pragma unroll
        for (int i = 0; i < 4; ++i) {
            float inv = 1.f / lsum[ma][i];
            size_t orow = (rowbase + qrow_w + ma * 16 + lrow4 + i) * 2048 + h * 128;
#pragma unroll
            for (int n = 0; n < 8; ++n)
                att[orow + n * 16 + lr] = (bf16)(o[ma][n][i] * inv);
        }
}

// ---------------- host launch ----------------
extern "C" void kernel_launch(void* const* d_in, const int* in_sizes, int n_in,
                              void* d_out, int out_size, void* d_ws, size_t ws_size,
                              hipStream_t stream)
{
    (void)in_sizes; (void)n_in; (void)out_size; (void)ws_size;
    const float* x = (const float*)d_in[0];
    const float* w_ckv = (const float*)d_in[1];
    const float* w_kv = (const float*)d_in[2];
    const float* w_cq = (const float*)d_in[3];
    const float* w_q = (const float*)d_in[4];
    const float* w_qr = (const float*)d_in[5];
    const float* w_kr = (const float*)d_in[6];
    const float* w_out = (const float*)d_in[7];
    float* out = (float*)d_out;

    char* ws = (char*)d_ws;
    size_t off = 0;
    auto take = [&](size_t elems) -> bf16* {
        bf16* p = (bf16*)(ws + off);
        off += (elems * sizeof(bf16) + 255) & ~(size_t)255;
        return p;
    };
    // merged transposed weights
    bf16* WCT    = take(1024ull * 2048);   // [ckv|cq]^T
    bf16* WKVKRT = take(4160ull * 512);    // [kv|kr]^T
    bf16* WQQRT  = take(3072ull * 512);    // [q|qr]^T
    bf16* C      = take(4096ull * 1024);   // [c_kv | c_q] packed, stride 1024
    bf16* KVKR   = take(4096ull * 4160);   // [k_c | v | k_r] packed, stride 4160
    bf16* QCR    = take(4096ull * 3072);   // [q_c | q_r] packed, stride 3072
    bf16* ATT    = take(4096ull * 2048);
    bf16* WOUTT  = C;  // 8 MB alias (C dead after the two K=512 GEMMs)

    auto cvtT = [&](const float* in, bf16* o, int K, int N) {
        k_cvtT<<<dim3(N / 32, K / 32), 256, 0, stream>>>(in, o, K, N);
    };
    cvtT(w_ckv, WCT, 2048, 512);
    cvtT(w_cq, WCT + 512ull * 2048, 2048, 512);
    cvtT(w_kv, WKVKRT, 512, 4096);
    cvtT(w_kr, WKVKRT + 4096ull * 512, 512, 64);
    cvtT(w_q, WQQRT, 512, 2048);
    cvtT(w_qr, WQQRT + 2048ull * 512, 512, 1024);

    // C = x @ [W_ckv | W_cq]   (M=4096, N=1024, K=2048, A=f32)
    k_gemm_bt<true, false><<<dim3(8, 32), 256, 0, stream>>>(
        nullptr, x, WCT, C, nullptr, 4096, 1024, 2048, 2048);
    // KVKR = c_kv @ [W_kv | W_kr]   (N=4160, K=512)
    k_gemm_bt<false, false><<<dim3(33, 32), 256, 0, stream>>>(
        C, nullptr, WKVKRT, KVKR, nullptr, 4096, 4160, 512, 1024);
    // QCR = c_q @ [W_q | W_qr]   (N=3072, K=512)
    k_gemm_bt<false, false><<<dim3(24, 32), 256, 0, stream>>>(
        C + 512, nullptr, WQQRT, QCR, nullptr, 4096, 3072, 512, 1024);

    cvtT(w_out, WOUTT, 2048, 2048);  // safe: C dead now

    k_rope_q<<<8192, 256, 0, stream>>>(QCR);
    k_rope_k<<<512, 256, 0, stream>>>(KVKR);

    k_attn<<<512, 256, 0, stream>>>(QCR, KVKR, ATT);

    // out = att @ W_out   (N=2048, K=2048, f32 out)
    k_gemm_bt<false, true><<<dim3(16, 32), 256, 0, stream>>>(
        ATT, nullptr, WOUTT, nullptr, out, 4096, 2048, 2048, 2048);
}

// Round 6
// 328.885 us; speedup vs baseline: 1.0863x; 1.0863x over previous
//
#include <hip/hip_runtime.h>
#include <hip/hip_bf16.h>
#include <cstdint>
#include <cstddef>

typedef __bf16 bf16;
typedef __attribute__((ext_vector_type(2))) __bf16 bf16x2;
typedef __attribute__((ext_vector_type(4))) __bf16 bf16x4;
typedef __attribute__((ext_vector_type(8))) __bf16 bf16x8;
typedef __attribute__((ext_vector_type(4))) float f32x4;

#define MFMA16(a, b, c) __builtin_amdgcn_mfma_f32_16x16x32_bf16((a), (b), (c), 0, 0, 0)
// softmax runs in exp2 domain: scores scaled by (1/sqrt(128))*log2(e)
#define SCALE_L2E 0.127517432f

// Packed-layout constants:
//  QCR row: [0..2047]=q_c (h*128+d), [2048..3071]=q_r (h*64+r)    stride 3072
//  KVKR row: [0..2047]=k_c, [2048..4095]=v, [4096..4159]=k_r      stride 4160
#define QCR_STRIDE 3072
#define KV_STRIDE  4160

__device__ __forceinline__ void gload16(const void* g, void* l) {
    __builtin_amdgcn_global_load_lds(
        (const __attribute__((address_space(1))) void*)g,
        (__attribute__((address_space(3))) void*)l, 16, 0, 0);
}

// ---------------- f32 -> bf16 transpose-convert (weights) ----------------
__global__ __launch_bounds__(256) void k_cvtT(const float* __restrict__ in,
                                              bf16* __restrict__ out, int Kd, int Nd)
{
    __shared__ float tile[32][33];
    const int k0 = blockIdx.y * 32, n0 = blockIdx.x * 32;
    const int t = threadIdx.x;
    const int r = t >> 3, c4 = (t & 7) * 4;
    float4 v = *(const float4*)(in + (size_t)(k0 + r) * Nd + n0 + c4);
    tile[r][c4 + 0] = v.x; tile[r][c4 + 1] = v.y;
    tile[r][c4 + 2] = v.z; tile[r][c4 + 3] = v.w;
    __syncthreads();
    bf16x4 o;
    o[0] = (bf16)tile[c4 + 0][r]; o[1] = (bf16)tile[c4 + 1][r];
    o[2] = (bf16)tile[c4 + 2][r]; o[3] = (bf16)tile[c4 + 3][r];
    *(bf16x4*)(out + (size_t)(n0 + r) * Kd + k0 + c4) = o;
}

// ---------------- bf16 MFMA GEMM, B pre-transposed, 2-phase dbuf ----------------
template<bool AF32, bool F32OUT>
__global__ __launch_bounds__(256) void k_gemm_bt(
    const bf16* __restrict__ A, const float* __restrict__ Af,
    const bf16* __restrict__ BT,
    bf16* __restrict__ Cb, float* __restrict__ Cf,
    int M, int N, int K, int lda)
{
    __shared__ bf16 As[2][4096];   // [128 rows][32 k] linear
    __shared__ bf16 Bs[2][4096];   // [128 n-rows][32 k] linear

    const int t = threadIdx.x;
    const int m0 = blockIdx.y * 128;
    const int n0 = blockIdx.x * 128;
    const int wid = t >> 6, lane = t & 63;
    const int wm = (wid >> 1) * 64, wn = (wid & 1) * 64;
    const int lr = lane & 15, lk = (lane >> 4) * 8;

    const int srow = t >> 2, skc = (t & 3) << 3;
    const int bn0 = min(n0 + srow, N - 1);
    const int bn1 = min(n0 + srow + 64, N - 1);

    f32x4 acc[4][4];
    const f32x4 z = {0.f, 0.f, 0.f, 0.f};
#pragma unroll
    for (int m = 0; m < 4; ++m)
#pragma unroll
        for (int n = 0; n < 4; ++n) acc[m][n] = z;

    auto stage = [&](int buf, int k0) {
        gload16(BT + (size_t)bn0 * K + k0 + skc, &Bs[buf][t * 8]);
        gload16(BT + (size_t)bn1 * K + k0 + skc, &Bs[buf][(t + 256) * 8]);
        if constexpr (AF32) {
            const float* s0 = Af + (size_t)(m0 + srow) * lda + k0 + skc;
            float4 u0 = *(const float4*)s0;
            float4 u1 = *(const float4*)(s0 + 4);
            bf16x8 v;
            v[0] = (bf16)u0.x; v[1] = (bf16)u0.y; v[2] = (bf16)u0.z; v[3] = (bf16)u0.w;
            v[4] = (bf16)u1.x; v[5] = (bf16)u1.y; v[6] = (bf16)u1.z; v[7] = (bf16)u1.w;
            *(bf16x8*)(&As[buf][t * 8]) = v;
            const float* s1 = Af + (size_t)(m0 + srow + 64) * lda + k0 + skc;
            float4 w0 = *(const float4*)s1;
            float4 w1 = *(const float4*)(s1 + 4);
            bf16x8 v2;
            v2[0] = (bf16)w0.x; v2[1] = (bf16)w0.y; v2[2] = (bf16)w0.z; v2[3] = (bf16)w0.w;
            v2[4] = (bf16)w1.x; v2[5] = (bf16)w1.y; v2[6] = (bf16)w1.z; v2[7] = (bf16)w1.w;
            *(bf16x8*)(&As[buf][(t + 256) * 8]) = v2;
        } else {
            gload16(A + (size_t)(m0 + srow) * lda + k0 + skc, &As[buf][t * 8]);
            gload16(A + (size_t)(m0 + srow + 64) * lda + k0 + skc, &As[buf][(t + 256) * 8]);
        }
    };

    stage(0, 0);
    __syncthreads();

    for (int k0 = 0; k0 < K; k0 += 32) {
        const int cur = (k0 >> 5) & 1;
        if (k0 + 32 < K) stage(cur ^ 1, k0 + 32);

        bf16x8 af[4], bfr[4];
#pragma unroll
        for (int m = 0; m < 4; ++m) af[m] = *(const bf16x8*)(&As[cur][(wm + m * 16 + lr) * 32 + lk]);
#pragma unroll
        for (int n = 0; n < 4; ++n) bfr[n] = *(const bf16x8*)(&Bs[cur][(wn + n * 16 + lr) * 32 + lk]);
#pragma unroll
        for (int m = 0; m < 4; ++m)
#pragma unroll
            for (int n = 0; n < 4; ++n)
                acc[m][n] = MFMA16(af[m], bfr[n], acc[m][n]);

        __syncthreads();
    }

    const int lrow4 = (lane >> 4) * 4;
#pragma unroll
    for (int m = 0; m < 4; ++m)
#pragma unroll
        for (int n = 0; n < 4; ++n)
#pragma unroll
            for (int i = 0; i < 4; ++i) {
                int r = m0 + wm + m * 16 + lrow4 + i;
                int c = n0 + wn + n * 16 + lr;
                if (r < M && c < N) {
                    if constexpr (F32OUT) Cf[(size_t)r * N + c] = acc[m][n][i];
                    else Cb[(size_t)r * N + c] = (bf16)acc[m][n][i];
                }
            }
}

// ---------------- RoPE (in-place, bf16, packed layouts) ----------------
__global__ void k_rope_q(bf16* __restrict__ qcr)
{
    int idx = blockIdx.x * blockDim.x + threadIdx.x;  // 4096*512 threads
    int row = idx >> 9;
    int rem = idx & 511;
    int h = rem >> 5;
    int i = rem & 31;
    int s = row & 2047;
    float ang = (float)s * __expf(-(float)i * 0.28782313662f);  // ln(10000)/32
    float c = cosf(ang), sn = sinf(ang);
    size_t base = (size_t)row * QCR_STRIDE + 2048 + h * 64 + (i << 1);
    float xe = (float)qcr[base], xo = (float)qcr[base + 1];
    qcr[base] = (bf16)(xe * c - xo * sn);
    qcr[base + 1] = (bf16)(xe * sn + xo * c);
}

__global__ void k_rope_k(bf16* __restrict__ kvkr)
{
    int idx = blockIdx.x * blockDim.x + threadIdx.x;  // 4096*32 threads
    int row = idx >> 5;
    int i = idx & 31;
    int s = row & 2047;
    float ang = (float)s * __expf(-(float)i * 0.28782313662f);
    float c = cosf(ang), sn = sinf(ang);
    size_t base = (size_t)row * KV_STRIDE + 4096 + (i << 1);
    float xe = (float)kvkr[base], xo = (float)kvkr[base + 1];
    kvkr[base] = (bf16)(xe * c - xo * sn);
    kvkr[base + 1] = (bf16)(xe * sn + xo * c);
}

// ---------------- causal MLA attention ----------------
// 256 blocks x 512 threads (8 waves x 16 q-rows = 128-row q-tile).
// Block L: p = L>>5 (0..7), bh = L&31 -> same-(b,h) blocks share L%8 (same XCD).
// Two passes: qt = p and qt = 15-p  -> every block stages exactly 34 KV tiles.
// T14 async-stage: tile kt+1's global loads issued under tile kt's compute.
__global__ __launch_bounds__(512, 2) void k_attn(
    const bf16* __restrict__ qcr, const bf16* __restrict__ kvkr,
    bf16* __restrict__ att)
{
    __shared__ bf16 Ks[64 * 200];   // [key][feat 0..191], stride 200
    __shared__ bf16 Vt[128 * 72];   // [feat][key], stride 72
    __shared__ bf16 Pw[8][16 * 72]; // per-wave P tile [16 rows][64 keys]

    const int L = blockIdx.x;
    const int p = L >> 5;
    const int bh = L & 31;
    const int h = bh & 15, b = bh >> 4;

    const int t = threadIdx.x;
    const int wid = t >> 6, lane = t & 63;
    const int lr = lane & 15, lk = (lane >> 4) * 8, lrow4 = (lane >> 4) * 4;
    const size_t rowbase = (size_t)b * 2048;

    // staging decomposition (512 threads)
    const int kcrow0 = t >> 4, kcfc = (t & 15) << 3;   // K_c: rows t>>4 and +32
    const int krrow = t >> 3, krfc = (t & 7) << 3;     // K_r
    const int vrow = (t & 31) * 2, vfc = (t >> 5) * 8; // V: 2 rows, 8 feats

    const f32x4 z = {0.f, 0.f, 0.f, 0.f};

    bf16x8 rc0, rc1, rr, rv0, rv1;   // staging registers (T14 split)

    auto LOAD = [&](int kb) {
        rc0 = *(const bf16x8*)(kvkr + (rowbase + kb + kcrow0) * KV_STRIDE + h * 128 + kcfc);
        rc1 = *(const bf16x8*)(kvkr + (rowbase + kb + kcrow0 + 32) * KV_STRIDE + h * 128 + kcfc);
        rr  = *(const bf16x8*)(kvkr + (rowbase + kb + krrow) * KV_STRIDE + 4096 + krfc);
        const bf16* vs = kvkr + (rowbase + kb + vrow) * KV_STRIDE + 2048 + h * 128 + vfc;
        rv0 = *(const bf16x8*)vs;
        rv1 = *(const bf16x8*)(vs + KV_STRIDE);
    };
    auto WRITE = [&]() {
        *(bf16x8*)(Ks + kcrow0 * 200 + kcfc) = rc0;
        *(bf16x8*)(Ks + (kcrow0 + 32) * 200 + kcfc) = rc1;
        *(bf16x8*)(Ks + krrow * 200 + 128 + krfc) = rr;
#pragma unroll
        for (int j = 0; j < 8; ++j) {
            bf16x2 pr; pr[0] = rv0[j]; pr[1] = rv1[j];
            *(bf16x2*)(Vt + (vfc + j) * 72 + vrow) = pr;
        }
    };

#pragma unroll 1
    for (int pass = 0; pass < 2; ++pass) {
        const int qt = pass ? 15 - p : p;
        const int qrow_w = qt * 128 + wid * 16;

        // Q fragments (16 rows/wave)
        bf16x8 qf[6];
        {
            const size_t qrow = rowbase + qrow_w + lr;
            const bf16* qp = qcr + qrow * QCR_STRIDE + h * 128;
#pragma unroll
            for (int ks = 0; ks < 4; ++ks) qf[ks] = *(const bf16x8*)(qp + ks * 32 + lk);
            const bf16* qp2 = qcr + qrow * QCR_STRIDE + 2048 + h * 64;
#pragma unroll
            for (int ks = 0; ks < 2; ++ks) qf[4 + ks] = *(const bf16x8*)(qp2 + ks * 32 + lk);
        }

        float mrow[4], lsum[4];
        f32x4 o[8];
#pragma unroll
        for (int i = 0; i < 4; ++i) { mrow[i] = -3e38f; lsum[i] = 0.f; }
#pragma unroll
        for (int n = 0; n < 8; ++n) o[n] = z;

        const int nkt = 2 * qt + 2;
        LOAD(0);
#pragma unroll 1
        for (int kt = 0; kt < nkt; ++kt) {
            const int kb = kt * 64;
            __syncthreads();                 // previous tile's compute done with LDS
            WRITE();
            if (kt + 1 < nkt) LOAD(kb + 64); // async under this tile's compute
            __syncthreads();                 // staged tile visible

            if (kb > qrow_w + 15) continue;  // tile fully above this wave's rows

            // ---- S = Q K^T ----
            f32x4 sacc[4];
#pragma unroll
            for (int kg = 0; kg < 4; ++kg) {
                f32x4 s = z;
#pragma unroll
                for (int ks = 0; ks < 6; ++ks) {
                    bf16x8 kf = *(const bf16x8*)(Ks + (kg * 16 + lr) * 200 + ks * 32 + lk);
                    s = MFMA16(qf[ks], kf, s);
                }
                sacc[kg] = s;
            }

            // ---- scale (exp2 domain) + causal mask + row max ----
            const bool domask = (kb + 63) > qrow_w;
            float rmax[4];
#pragma unroll
            for (int i = 0; i < 4; ++i) {
                int qi = qrow_w + lrow4 + i;
                float mx = -3e38f;
#pragma unroll
                for (int kg = 0; kg < 4; ++kg) {
                    float v = sacc[kg][i] * SCALE_L2E;
                    if (domask && (kb + kg * 16 + lr) > qi) v = -3e38f;
                    sacc[kg][i] = v;
                    mx = fmaxf(mx, v);
                }
                rmax[i] = mx;
            }
#pragma unroll
            for (int d = 1; d < 16; d <<= 1)
#pragma unroll
                for (int i = 0; i < 4; ++i)
                    rmax[i] = fmaxf(rmax[i], __shfl_xor(rmax[i], d, 64));

            // ---- defer-max: rescale only if some row got a new max ----
            int anynew = 0;
#pragma unroll
            for (int i = 0; i < 4; ++i)
                if (rmax[i] > mrow[i]) anynew = 1;
            if (__any(anynew)) {
#pragma unroll
                for (int i = 0; i < 4; ++i) {
                    float mnew = fmaxf(mrow[i], rmax[i]);
                    float scl = __builtin_amdgcn_exp2f(mrow[i] - mnew);
                    mrow[i] = mnew;
                    lsum[i] *= scl;
#pragma unroll
                    for (int n = 0; n < 8; ++n) o[n][i] *= scl;
                }
            }

            // ---- P = exp2(S - m), row sums ----
            float rsum[4] = {0.f, 0.f, 0.f, 0.f};
#pragma unroll
            for (int kg = 0; kg < 4; ++kg)
#pragma unroll
                for (int i = 0; i < 4; ++i) {
                    float pv = __builtin_amdgcn_exp2f(sacc[kg][i] - mrow[i]);
                    sacc[kg][i] = pv;
                    rsum[i] += pv;
                }
#pragma unroll
            for (int d = 1; d < 16; d <<= 1)
#pragma unroll
                for (int i = 0; i < 4; ++i) rsum[i] += __shfl_xor(rsum[i], d, 64);
#pragma unroll
            for (int i = 0; i < 4; ++i) lsum[i] += rsum[i];

            // ---- P -> per-wave LDS (re-fragment for PV A-operand) ----
#pragma unroll
            for (int kg = 0; kg < 4; ++kg)
#pragma unroll
                for (int i = 0; i < 4; ++i)
                    Pw[wid][(lrow4 + i) * 72 + kg * 16 + lr] = (bf16)sacc[kg][i];

            // ---- O += P V ----
#pragma unroll
            for (int ks = 0; ks < 2; ++ks) {
                bf16x8 pa = *(const bf16x8*)(&Pw[wid][lr * 72 + ks * 32 + lk]);
#pragma unroll
                for (int n = 0; n < 8; ++n) {
                    bf16x8 vf = *(const bf16x8*)(Vt + (n * 16 + lr) * 72 + ks * 32 + lk);
                    o[n] = MFMA16(pa, vf, o[n]);
                }
            }
        }

#pragma unroll
        for (int i = 0; i < 4; ++i) {
            float inv = 1.f / lsum[i];
            size_t orow = (rowbase + qrow_w + lrow4 + i) * 2048 + h * 128;
#pragma unroll
            for (int n = 0; n < 8; ++n)
                att[orow + n * 16 + lr] = (bf16)(o[n][i] * inv);
        }
    }
}

// ---------------- host launch ----------------
extern "C" void kernel_launch(void* const* d_in, const int* in_sizes, int n_in,
                              void* d_out, int out_size, void* d_ws, size_t ws_size,
                              hipStream_t stream)
{
    (void)in_sizes; (void)n_in; (void)out_size; (void)ws_size;
    const float* x = (const float*)d_in[0];
    const float* w_ckv = (const float*)d_in[1];
    const float* w_kv = (const float*)d_in[2];
    const float* w_cq = (const float*)d_in[3];
    const float* w_q = (const float*)d_in[4];
    const float* w_qr = (const float*)d_in[5];
    const float* w_kr = (const float*)d_in[6];
    const float* w_out = (const float*)d_in[7];
    float* out = (float*)d_out;

    char* ws = (char*)d_ws;
    size_t off = 0;
    auto take = [&](size_t elems) -> bf16* {
        bf16* p = (bf16*)(ws + off);
        off += (elems * sizeof(bf16) + 255) & ~(size_t)255;
        return p;
    };
    // merged transposed weights
    bf16* WCT    = take(1024ull * 2048);   // [ckv|cq]^T
    bf16* WKVKRT = take(4160ull * 512);    // [kv|kr]^T
    bf16* WQQRT  = take(3072ull * 512);    // [q|qr]^T
    bf16* C      = take(4096ull * 1024);   // [c_kv | c_q] packed, stride 1024
    bf16* KVKR   = take(4096ull * 4160);   // [k_c | v | k_r] packed, stride 4160
    bf16* QCR    = take(4096ull * 3072);   // [q_c | q_r] packed, stride 3072
    bf16* ATT    = take(4096ull * 2048);
    bf16* WOUTT  = C;  // 8 MB alias (C dead after the two K=512 GEMMs)

    auto cvtT = [&](const float* in, bf16* o, int K, int N) {
        k_cvtT<<<dim3(N / 32, K / 32), 256, 0, stream>>>(in, o, K, N);
    };
    cvtT(w_ckv, WCT, 2048, 512);
    cvtT(w_cq, WCT + 512ull * 2048, 2048, 512);
    cvtT(w_kv, WKVKRT, 512, 4096);
    cvtT(w_kr, WKVKRT + 4096ull * 512, 512, 64);
    cvtT(w_q, WQQRT, 512, 2048);
    cvtT(w_qr, WQQRT + 2048ull * 512, 512, 1024);

    // C = x @ [W_ckv | W_cq]   (M=4096, N=1024, K=2048, A=f32)
    k_gemm_bt<true, false><<<dim3(8, 32), 256, 0, stream>>>(
        nullptr, x, WCT, C, nullptr, 4096, 1024, 2048, 2048);
    // KVKR = c_kv @ [W_kv | W_kr]   (N=4160, K=512)
    k_gemm_bt<false, false><<<dim3(33, 32), 256, 0, stream>>>(
        C, nullptr, WKVKRT, KVKR, nullptr, 4096, 4160, 512, 1024);
    // QCR = c_q @ [W_q | W_qr]   (N=3072, K=512)
    k_gemm_bt<false, false><<<dim3(24, 32), 256, 0, stream>>>(
        C + 512, nullptr, WQQRT, QCR, nullptr, 4096, 3072, 512, 1024);

    cvtT(w_out, WOUTT, 2048, 2048);  // safe: C dead now

    k_rope_q<<<8192, 256, 0, stream>>>(QCR);
    k_rope_k<<<512, 256, 0, stream>>>(KVKR);

    k_attn<<<256, 512, 0, stream>>>(QCR, KVKR, ATT);

    // out = att @ W_out   (N=2048, K=2048, f32 out)
    k_gemm_bt<false, true><<<dim3(16, 32), 256, 0, stream>>>(
        ATT, nullptr, WOUTT, nullptr, out, 4096, 2048, 2048, 2048);
}

// Round 7
// 292.379 us; speedup vs baseline: 1.2219x; 1.1249x over previous
//
#include <hip/hip_runtime.h>
#include <hip/hip_bf16.h>
#include <cstdint>
#include <cstddef>

typedef __bf16 bf16;
typedef __attribute__((ext_vector_type(2))) __bf16 bf16x2;
typedef __attribute__((ext_vector_type(4))) __bf16 bf16x4;
typedef __attribute__((ext_vector_type(8))) __bf16 bf16x8;
typedef __attribute__((ext_vector_type(4))) float f32x4;

#define MFMA16(a, b, c) __builtin_amdgcn_mfma_f32_16x16x32_bf16((a), (b), (c), 0, 0, 0)
// softmax runs in exp2 domain: scores scaled by (1/sqrt(128))*log2(e)
#define SCALE_L2E 0.127517432f

// Packed-layout constants:
//  QCR row: [0..2047]=q_c (h*128+d), [2048..3071]=q_r (h*64+r)    stride 3072
//  KVKR row: [0..2047]=k_c, [2048..4095]=v, [4096..4159]=k_r      stride 4160
#define QCR_STRIDE 3072
#define KV_STRIDE  4160

__device__ __forceinline__ void gload16(const void* g, void* l) {
    __builtin_amdgcn_global_load_lds(
        (const __attribute__((address_space(1))) void*)g,
        (__attribute__((address_space(3))) void*)l, 16, 0, 0);
}

// barrier WITHOUT vmcnt drain: my LDS ops done -> sync -> fence reordering.
// (hipcc's __syncthreads emits vmcnt(0) which would drain the async prefetch.)
__device__ __forceinline__ void bar_lgkm() {
    asm volatile("s_waitcnt lgkmcnt(0)" ::: "memory");
    __builtin_amdgcn_s_barrier();
    asm volatile("" ::: "memory");
}

// ---------------- f32 -> bf16 straight convert (x) ----------------
__global__ void k_cvt(const float* __restrict__ in, bf16* __restrict__ out, int n4)
{
    int i = blockIdx.x * blockDim.x + threadIdx.x;
    int stride = gridDim.x * blockDim.x;
    const float4* in4 = (const float4*)in;
    bf16x4* o4 = (bf16x4*)out;
    for (; i < n4; i += stride) {
        float4 v = in4[i];
        bf16x4 o;
        o[0] = (bf16)v.x; o[1] = (bf16)v.y; o[2] = (bf16)v.z; o[3] = (bf16)v.w;
        o4[i] = o;
    }
}

// ---------------- f32 -> bf16 transpose-convert (weights) ----------------
__global__ __launch_bounds__(256) void k_cvtT(const float* __restrict__ in,
                                              bf16* __restrict__ out, int Kd, int Nd)
{
    __shared__ float tile[32][33];
    const int k0 = blockIdx.y * 32, n0 = blockIdx.x * 32;
    const int t = threadIdx.x;
    const int r = t >> 3, c4 = (t & 7) * 4;
    float4 v = *(const float4*)(in + (size_t)(k0 + r) * Nd + n0 + c4);
    tile[r][c4 + 0] = v.x; tile[r][c4 + 1] = v.y;
    tile[r][c4 + 2] = v.z; tile[r][c4 + 3] = v.w;
    __syncthreads();
    bf16x4 o;
    o[0] = (bf16)tile[c4 + 0][r]; o[1] = (bf16)tile[c4 + 1][r];
    o[2] = (bf16)tile[c4 + 2][r]; o[3] = (bf16)tile[c4 + 3][r];
    *(bf16x4*)(out + (size_t)(n0 + r) * Kd + k0 + c4) = o;
}

// ---------------- bf16 MFMA GEMM, B pre-transposed, 2-phase dbuf ----------------
// C[M,N] = A[M,K] @ B[K,N], given BT[N][K] row-major.  Tile 128 x (NF*32).
template<int NF, bool F32OUT>
__global__ __launch_bounds__(256) void k_gemm_bt(
    const bf16* __restrict__ A, const bf16* __restrict__ BT,
    bf16* __restrict__ Cb, float* __restrict__ Cf,
    int M, int N, int K, int lda)
{
    __shared__ bf16 As[2][4096];        // [128 rows][32 k] linear
    __shared__ bf16 Bs[2][NF * 1024];   // [NF*32 n-rows][32 k] linear

    const int t = threadIdx.x;
    const int m0 = blockIdx.y * 128;
    const int n0 = blockIdx.x * (NF * 32);
    const int wid = t >> 6, lane = t & 63;
    const int wm = (wid >> 1) * 64, wn = (wid & 1) * (NF * 16);
    const int lr = lane & 15, lk = (lane >> 4) * 8;

    const int srow = t >> 2, skc = (t & 3) << 3;
    const int bn0 = min(n0 + srow, N - 1);
    const int bn1 = min(n0 + srow + 64, N - 1);

    f32x4 acc[4][NF];
    const f32x4 z = {0.f, 0.f, 0.f, 0.f};
#pragma unroll
    for (int m = 0; m < 4; ++m)
#pragma unroll
        for (int n = 0; n < NF; ++n) acc[m][n] = z;

    auto stage = [&](int buf, int k0) {
        gload16(BT + (size_t)bn0 * K + k0 + skc, &Bs[buf][t * 8]);
        if constexpr (NF == 4)
            gload16(BT + (size_t)bn1 * K + k0 + skc, &Bs[buf][(t + 256) * 8]);
        gload16(A + (size_t)(m0 + srow) * lda + k0 + skc, &As[buf][t * 8]);
        gload16(A + (size_t)(m0 + srow + 64) * lda + k0 + skc, &As[buf][(t + 256) * 8]);
    };

    stage(0, 0);
    __syncthreads();

    for (int k0 = 0; k0 < K; k0 += 32) {
        const int cur = (k0 >> 5) & 1;
        if (k0 + 32 < K) stage(cur ^ 1, k0 + 32);

        bf16x8 af[4], bfr[NF];
#pragma unroll
        for (int m = 0; m < 4; ++m) af[m] = *(const bf16x8*)(&As[cur][(wm + m * 16 + lr) * 32 + lk]);
#pragma unroll
        for (int n = 0; n < NF; ++n) bfr[n] = *(const bf16x8*)(&Bs[cur][(wn + n * 16 + lr) * 32 + lk]);
#pragma unroll
        for (int m = 0; m < 4; ++m)
#pragma unroll
            for (int n = 0; n < NF; ++n)
                acc[m][n] = MFMA16(af[m], bfr[n], acc[m][n]);

        __syncthreads();
    }

    const int lrow4 = (lane >> 4) * 4;
#pragma unroll
    for (int m = 0; m < 4; ++m)
#pragma unroll
        for (int n = 0; n < NF; ++n)
#pragma unroll
            for (int i = 0; i < 4; ++i) {
                int r = m0 + wm + m * 16 + lrow4 + i;
                int c = n0 + wn + n * 16 + lr;
                if (r < M && c < N) {
                    if constexpr (F32OUT) Cf[(size_t)r * N + c] = acc[m][n][i];
                    else Cb[(size_t)r * N + c] = (bf16)acc[m][n][i];
                }
            }
}

// ---------------- RoPE (in-place, bf16, packed layouts) ----------------
__global__ void k_rope_q(bf16* __restrict__ qcr)
{
    int idx = blockIdx.x * blockDim.x + threadIdx.x;  // 4096*512 threads
    int row = idx >> 9;
    int rem = idx & 511;
    int h = rem >> 5;
    int i = rem & 31;
    int s = row & 2047;
    float ang = (float)s * __expf(-(float)i * 0.28782313662f);  // ln(10000)/32
    float c = cosf(ang), sn = sinf(ang);
    size_t base = (size_t)row * QCR_STRIDE + 2048 + h * 64 + (i << 1);
    float xe = (float)qcr[base], xo = (float)qcr[base + 1];
    qcr[base] = (bf16)(xe * c - xo * sn);
    qcr[base + 1] = (bf16)(xe * sn + xo * c);
}

__global__ void k_rope_k(bf16* __restrict__ kvkr)
{
    int idx = blockIdx.x * blockDim.x + threadIdx.x;  // 4096*32 threads
    int row = idx >> 5;
    int i = idx & 31;
    int s = row & 2047;
    float ang = (float)s * __expf(-(float)i * 0.28782313662f);
    float c = cosf(ang), sn = sinf(ang);
    size_t base = (size_t)row * KV_STRIDE + 4096 + (i << 1);
    float xe = (float)kvkr[base], xo = (float)kvkr[base + 1];
    kvkr[base] = (bf16)(xe * c - xo * sn);
    kvkr[base + 1] = (bf16)(xe * sn + xo * c);
}

// ---------------- causal MLA attention ----------------
// 256 blocks x 512 threads (8 waves x 16 q-rows = 128-row q-tile).
// Block L: p = L>>5 (0..7), bh = L&31. Passes qt=p and qt=15-p -> 17 staged
// 128-key tiles per block (uniform). Single-buffered K/V LDS; per tile:
//   bar_lgkm; WRITE(regs->LDS); LOAD(next tile -> regs, stays in flight
//   across the barrier: bar_lgkm does NOT drain vmcnt); bar_lgkm; compute.
__global__ __launch_bounds__(512, 2) void k_attn(
    const bf16* __restrict__ qcr, const bf16* __restrict__ kvkr,
    bf16* __restrict__ att)
{
    __shared__ bf16 Ks[128 * 200];   // [key][feat 0..191], stride 200
    __shared__ bf16 Vt[128 * 136];   // [feat][key], stride 136
    __shared__ bf16 Pw[8][16 * 136]; // per-wave P tile [16 rows][128 keys]

    const int L = blockIdx.x;
    const int p = L >> 5;
    const int bh = L & 31;
    const int h = bh & 15, b = bh >> 4;

    const int t = threadIdx.x;
    const int wid = t >> 6, lane = t & 63;
    const int lr = lane & 15, lk = (lane >> 4) * 8, lrow4 = (lane >> 4) * 4;
    const size_t rowbase = (size_t)b * 2048;

    // staging decomposition (512 threads, 128-key tile)
    const int kcrow = t >> 4, kcfc = (t & 15) << 3;  // K_c rows +0/32/64/96
    const int krrow = t >> 3, krfc = (t & 7) << 3;   // K_r rows +0/64
    const int vk = (t & 63) * 2;                     // key pair
    const int vf = (t >> 6) * 8;                     // feat chunk (+64 2nd it)

    const f32x4 z = {0.f, 0.f, 0.f, 0.f};

    bf16x8 rc[4], rr[2], rv[4];   // staging registers
    auto LOAD = [&](int kb) {
#pragma unroll
        for (int i = 0; i < 4; ++i)
            rc[i] = *(const bf16x8*)(kvkr + (rowbase + kb + kcrow + 32 * i) * KV_STRIDE + h * 128 + kcfc);
#pragma unroll
        for (int i = 0; i < 2; ++i)
            rr[i] = *(const bf16x8*)(kvkr + (rowbase + kb + krrow + 64 * i) * KV_STRIDE + 4096 + krfc);
#pragma unroll
        for (int i = 0; i < 2; ++i) {
            const bf16* vs = kvkr + (rowbase + kb + vk) * KV_STRIDE + 2048 + h * 128 + vf + 64 * i;
            rv[2 * i]     = *(const bf16x8*)vs;
            rv[2 * i + 1] = *(const bf16x8*)(vs + KV_STRIDE);
        }
    };
    auto WRITE = [&]() {
#pragma unroll
        for (int i = 0; i < 4; ++i)
            *(bf16x8*)(Ks + (kcrow + 32 * i) * 200 + kcfc) = rc[i];
#pragma unroll
        for (int i = 0; i < 2; ++i)
            *(bf16x8*)(Ks + (krrow + 64 * i) * 200 + 128 + krfc) = rr[i];
#pragma unroll
        for (int i = 0; i < 2; ++i)
#pragma unroll
            for (int j = 0; j < 8; ++j) {
                bf16x2 pr; pr[0] = rv[2 * i][j]; pr[1] = rv[2 * i + 1][j];
                *(bf16x2*)(Vt + (vf + 64 * i + j) * 136 + vk) = pr;
            }
    };

    LOAD(0);

#pragma unroll 1
    for (int pass = 0; pass < 2; ++pass) {
        const int qt = pass ? 15 - p : p;
        const int qrow_w = qt * 128 + wid * 16;

        bf16x8 qf[6];
        {
            const size_t qrow = rowbase + qrow_w + lr;
            const bf16* qp = qcr + qrow * QCR_STRIDE + h * 128;
#pragma unroll
            for (int ks = 0; ks < 4; ++ks) qf[ks] = *(const bf16x8*)(qp + ks * 32 + lk);
            const bf16* qp2 = qcr + qrow * QCR_STRIDE + 2048 + h * 64;
#pragma unroll
            for (int ks = 0; ks < 2; ++ks) qf[4 + ks] = *(const bf16x8*)(qp2 + ks * 32 + lk);
        }

        float mrow[4], lsum[4];
        f32x4 o[8];
#pragma unroll
        for (int i = 0; i < 4; ++i) { mrow[i] = -3e38f; lsum[i] = 0.f; }
#pragma unroll
        for (int n = 0; n < 8; ++n) o[n] = z;

        const int nkt = qt + 1;
#pragma unroll 1
        for (int kt = 0; kt < nkt; ++kt) {
            const int kb = kt * 128;
            bar_lgkm();                       // all waves done reading prev tile
            WRITE();                          // counted vmcnt waits on staged regs
            if (kt + 1 < nkt) LOAD(kb + 128); // stays in flight across barrier
            else if (pass == 0) LOAD(0);      // prefetch pass-1 tile 0
            bar_lgkm();                       // writes visible

            // ---- S = Q K^T ----
            f32x4 sacc[8];
#pragma unroll
            for (int kg = 0; kg < 8; ++kg) {
                f32x4 s = z;
#pragma unroll
                for (int ks = 0; ks < 6; ++ks) {
                    bf16x8 kf = *(const bf16x8*)(Ks + (kg * 16 + lr) * 200 + ks * 32 + lk);
                    s = MFMA16(qf[ks], kf, s);
                }
                sacc[kg] = s;
            }

            // ---- scale (exp2 domain) + causal mask + row max ----
            const bool domask = (kb + 127) > qrow_w;   // only the diagonal tile
            float rmax[4];
#pragma unroll
            for (int i = 0; i < 4; ++i) {
                int qi = qrow_w + lrow4 + i;
                float mx = -3e38f;
#pragma unroll
                for (int kg = 0; kg < 8; ++kg) {
                    float v = sacc[kg][i] * SCALE_L2E;
                    if (domask && (kb + kg * 16 + lr) > qi) v = -3e38f;
                    sacc[kg][i] = v;
                    mx = fmaxf(mx, v);
                }
                rmax[i] = mx;
            }
#pragma unroll
            for (int d = 1; d < 16; d <<= 1)
#pragma unroll
                for (int i = 0; i < 4; ++i)
                    rmax[i] = fmaxf(rmax[i], __shfl_xor(rmax[i], d, 64));

            // ---- defer-max: rescale only if some row got a new max ----
            int anynew = 0;
#pragma unroll
            for (int i = 0; i < 4; ++i)
                if (rmax[i] > mrow[i]) anynew = 1;
            if (__any(anynew)) {
#pragma unroll
                for (int i = 0; i < 4; ++i) {
                    float mnew = fmaxf(mrow[i], rmax[i]);
                    float scl = __builtin_amdgcn_exp2f(mrow[i] - mnew);
                    mrow[i] = mnew;
                    lsum[i] *= scl;
#pragma unroll
                    for (int n = 0; n < 8; ++n) o[n][i] *= scl;
                }
            }

            // ---- P = exp2(S - m), row sums ----
            float rsum[4] = {0.f, 0.f, 0.f, 0.f};
#pragma unroll
            for (int kg = 0; kg < 8; ++kg)
#pragma unroll
                for (int i = 0; i < 4; ++i) {
                    float pv = __builtin_amdgcn_exp2f(sacc[kg][i] - mrow[i]);
                    sacc[kg][i] = pv;
                    rsum[i] += pv;
                }
#pragma unroll
            for (int d = 1; d < 16; d <<= 1)
#pragma unroll
                for (int i = 0; i < 4; ++i) rsum[i] += __shfl_xor(rsum[i], d, 64);
#pragma unroll
            for (int i = 0; i < 4; ++i) lsum[i] += rsum[i];

            // ---- P -> per-wave LDS (re-fragment for PV A-operand) ----
#pragma unroll
            for (int kg = 0; kg < 8; ++kg)
#pragma unroll
                for (int i = 0; i < 4; ++i)
                    Pw[wid][(lrow4 + i) * 136 + kg * 16 + lr] = (bf16)sacc[kg][i];

            // ---- O += P V ----
#pragma unroll
            for (int ks = 0; ks < 4; ++ks) {
                bf16x8 pa = *(const bf16x8*)(&Pw[wid][lr * 136 + ks * 32 + lk]);
#pragma unroll
                for (int n = 0; n < 8; ++n) {
                    bf16x8 vfr = *(const bf16x8*)(Vt + (n * 16 + lr) * 136 + ks * 32 + lk);
                    o[n] = MFMA16(pa, vfr, o[n]);
                }
            }
        }

#pragma unroll
        for (int i = 0; i < 4; ++i) {
            float inv = 1.f / lsum[i];
            size_t orow = (rowbase + qrow_w + lrow4 + i) * 2048 + h * 128;
#pragma unroll
            for (int n = 0; n < 8; ++n)
                att[orow + n * 16 + lr] = (bf16)(o[n][i] * inv);
        }
    }
}

// ---------------- host launch ----------------
extern "C" void kernel_launch(void* const* d_in, const int* in_sizes, int n_in,
                              void* d_out, int out_size, void* d_ws, size_t ws_size,
                              hipStream_t stream)
{
    (void)in_sizes; (void)n_in; (void)out_size; (void)ws_size;
    const float* x = (const float*)d_in[0];
    const float* w_ckv = (const float*)d_in[1];
    const float* w_kv = (const float*)d_in[2];
    const float* w_cq = (const float*)d_in[3];
    const float* w_q = (const float*)d_in[4];
    const float* w_qr = (const float*)d_in[5];
    const float* w_kr = (const float*)d_in[6];
    const float* w_out = (const float*)d_in[7];
    float* out = (float*)d_out;

    char* ws = (char*)d_ws;
    size_t off = 0;
    auto take = [&](size_t elems) -> bf16* {
        bf16* p = (bf16*)(ws + off);
        off += (elems * sizeof(bf16) + 255) & ~(size_t)255;
        return p;
    };
    // merged transposed weights
    bf16* WCT    = take(1024ull * 2048);   // [ckv|cq]^T
    bf16* WKVKRT = take(4160ull * 512);    // [kv|kr]^T
    bf16* WQQRT  = take(3072ull * 512);    // [q|qr]^T
    bf16* C      = take(4096ull * 1024);   // [c_kv | c_q] packed, stride 1024
    bf16* KVKR   = take(4096ull * 4160);   // [k_c | v | k_r] packed, stride 4160
    bf16* QCR    = take(4096ull * 3072);   // [q_c | q_r] packed, stride 3072
    bf16* ATT    = take(4096ull * 2048);
    bf16* WOUTT  = C;     // 8 MB alias (C dead after the two K=512 GEMMs)
    bf16* XB     = KVKR;  // 16.8 MB alias (XB dead before KVKR is written)

    auto cvtT = [&](const float* in, bf16* o, int K, int N) {
        k_cvtT<<<dim3(N / 32, K / 32), 256, 0, stream>>>(in, o, K, N);
    };
    cvtT(w_ckv, WCT, 2048, 512);
    cvtT(w_cq, WCT + 512ull * 2048, 2048, 512);
    cvtT(w_kv, WKVKRT, 512, 4096);
    cvtT(w_kr, WKVKRT + 4096ull * 512, 512, 64);
    cvtT(w_q, WQQRT, 512, 2048);
    cvtT(w_qr, WQQRT + 2048ull * 512, 512, 1024);

    // x -> bf16
    k_cvt<<<2048, 256, 0, stream>>>(x, XB, (4096 * 2048) / 4);

    // C = x @ [W_ckv | W_cq]   (M=4096, N=1024, K=2048; 128x64 tiles -> 512 blocks)
    k_gemm_bt<2, false><<<dim3(16, 32), 256, 0, stream>>>(
        XB, WCT, C, nullptr, 4096, 1024, 2048, 2048);
    // KVKR = c_kv @ [W_kv | W_kr]   (N=4160, K=512)
    k_gemm_bt<4, false><<<dim3(33, 32), 256, 0, stream>>>(
        C, WKVKRT, KVKR, nullptr, 4096, 4160, 512, 1024);
    // QCR = c_q @ [W_q | W_qr]   (N=3072, K=512)
    k_gemm_bt<4, false><<<dim3(24, 32), 256, 0, stream>>>(
        C + 512, WQQRT, QCR, nullptr, 4096, 3072, 512, 1024);

    cvtT(w_out, WOUTT, 2048, 2048);  // safe: C dead now

    k_rope_q<<<8192, 256, 0, stream>>>(QCR);
    k_rope_k<<<512, 256, 0, stream>>>(KVKR);

    k_attn<<<256, 512, 0, stream>>>(QCR, KVKR, ATT);

    // out = att @ W_out   (N=2048, K=2048, f32 out)
    k_gemm_bt<4, true><<<dim3(16, 32), 256, 0, stream>>>(
        ATT, WOUTT, nullptr, out, 4096, 2048, 2048, 2048);
}